// Round 2
// baseline (283.976 us; speedup 1.0000x reference)
//
#include <hip/hip_runtime.h>
#include <climits>

// BoundingBox: mask [128,1,512,512] fp32 -> bbox [128,4] int32 (ymin,xmin,ymax+1,xmax+1)
// THRESH = 0.5; if no pixel >= THRESH anywhere, result is (0,0,H,W).
//
// Single fused kernel: 2048 blocks (16 row-groups x 128 images), last block per
// image folds the per-image atomics and writes the final bbox. Mins are encoded
// as (511 - v) so ALL four reductions are atomicMax with a single 0xFF memset init.

#define THRESH 0.5f

static constexpr int N = 128;
static constexpr int H = 512;
static constexpr int W = 512;
static constexpr int G = 16;         // row-groups per image -> 128*16 = 2048 blocks (8/CU)
static constexpr int ROWS = H / G;   // 32 rows per block
static constexpr int BLK = 256;      // 4 waves
static constexpr int W4 = W / 4;     // 128 float4 column-groups per row

__global__ __launch_bounds__(BLK)
void bbox_fused(const float* __restrict__ mask, int* __restrict__ enc,
                int* __restrict__ cnt, int* __restrict__ out) {
    const int n = blockIdx.x;   // image
    const int g = blockIdx.y;   // row group
    const float4* base =
        (const float4*)(mask + (size_t)n * H * W + (size_t)g * ROWS * W);

    // Fixed-column assignment: thread owns column-group c across rows r0, r0+2, ...
    const int c  = threadIdx.x & (W4 - 1);   // 0..127
    const int r0 = threadIdx.x >> 7;         // 0..1

    int ymin = INT_MAX, ymax = -1;
    float m0 = 0.f, m1 = 0.f, m2 = 0.f, m3 = 0.f;  // column max accumulators

    #pragma unroll 4
    for (int r = r0; r < ROWS; r += 2) {
        float4 v = base[r * W4 + c];
        float mx = fmaxf(fmaxf(v.x, v.y), fmaxf(v.z, v.w));
        if (mx >= THRESH) {
            int h = g * ROWS + r;
            ymin = min(ymin, h);
            ymax = max(ymax, h);
        }
        m0 = fmaxf(m0, v.x); m1 = fmaxf(m1, v.y);
        m2 = fmaxf(m2, v.z); m3 = fmaxf(m3, v.w);
    }

    // xmin/xmax derived once from the accumulated column maxima.
    const int w = c << 2;
    int xmin = INT_MAX, xmax = -1;
    if (m0 >= THRESH) { xmin = w;               xmax = w;               }
    if (m1 >= THRESH) { xmin = min(xmin, w + 1); xmax = max(xmax, w + 1); }
    if (m2 >= THRESH) { xmin = min(xmin, w + 2); xmax = max(xmax, w + 2); }
    if (m3 >= THRESH) { xmin = min(xmin, w + 3); xmax = max(xmax, w + 3); }

    // Wave (64-lane) shuffle reduction.
    #pragma unroll
    for (int off = 32; off > 0; off >>= 1) {
        ymin = min(ymin, __shfl_down(ymin, off, 64));
        ymax = max(ymax, __shfl_down(ymax, off, 64));
        xmin = min(xmin, __shfl_down(xmin, off, 64));
        xmax = max(xmax, __shfl_down(xmax, off, 64));
    }

    __shared__ int s[BLK / 64][4];
    const int wave = threadIdx.x >> 6;
    const int lane = threadIdx.x & 63;
    if (lane == 0) {
        s[wave][0] = ymin; s[wave][1] = ymax; s[wave][2] = xmin; s[wave][3] = xmax;
    }
    __syncthreads();

    if (threadIdx.x == 0) {
        int a = s[0][0], b = s[0][1], cc = s[0][2], d = s[0][3];
        #pragma unroll
        for (int wv = 1; wv < BLK / 64; ++wv) {
            a  = min(a,  s[wv][0]); b = max(b, s[wv][1]);
            cc = min(cc, s[wv][2]); d = max(d, s[wv][3]);
        }
        int* e = enc + (n << 2);
        if (b >= 0) {  // this block saw at least one hit
            atomicMax(&e[0], (H - 1) - a);   // encoded ymin
            atomicMax(&e[1], b);             // ymax
            atomicMax(&e[2], (W - 1) - cc);  // encoded xmin
            atomicMax(&e[3], d);             // xmax
        }
        __threadfence();
        int old = atomicAdd(&cnt[n], 1);
        if (old == G - 1) {
            // Last block for this image: all contributions are visible.
            __threadfence();
            int e0 = atomicMax(&e[0], -1);   // atomic read (never modifies)
            int e1 = atomicMax(&e[1], -1);
            int e2 = atomicMax(&e[2], -1);
            int e3 = atomicMax(&e[3], -1);
            int4 r;
            if (e1 < 0) r = make_int4(0, 0, H, W);                            // no hit
            else        r = make_int4((H - 1) - e0, (W - 1) - e2, e1 + 1, e3 + 1);
            ((int4*)out)[n] = r;
        }
    }
}

extern "C" void kernel_launch(void* const* d_in, const int* in_sizes, int n_in,
                              void* d_out, int out_size, void* d_ws, size_t ws_size,
                              hipStream_t stream) {
    const float* mask = (const float*)d_in[0];
    int* enc = (int*)d_ws;                        // N*4 ints, init -1 (0xFF)
    int* cnt = (int*)((char*)d_ws + N * 4 * 4);   // N ints, init 0
    int* out = (int*)d_out;

    hipMemsetAsync(enc, 0xFF, N * 4 * sizeof(int), stream);
    hipMemsetAsync(cnt, 0x00, N * sizeof(int), stream);

    dim3 grid(N, G);
    bbox_fused<<<grid, BLK, 0, stream>>>(mask, enc, cnt, out);
}

// Round 3
// 189.439 us; speedup vs baseline: 1.4990x; 1.4990x over previous
//
#include <hip/hip_runtime.h>
#include <climits>

// BoundingBox: mask [128,1,512,512] fp32 -> bbox [128,4] int32 (ymin,xmin,ymax+1,xmax+1)
// THRESH = 0.5; if no pixel >= THRESH anywhere, result is (0,0,H,W).
//
// Two kernels, no atomics, no fences (R1's fused atomic+__threadfence tail
// serialized the whole kernel to 149us even when cache-warm).
// Main kernel: 2048 blocks, explicit 4-deep independent float4 load batches
// for MLP; x-extent via fixed-column fmaxf accumulators (column group
// c = tid & 127 is invariant under i += 256), y-extent via predicated min/max.

#define THRESH 0.5f

static constexpr int N = 128;
static constexpr int H = 512;
static constexpr int W = 512;
static constexpr int G = 16;         // row-groups per image -> 2048 blocks = 8/CU
static constexpr int ROWS = H / G;   // 32 rows per block
static constexpr int BLK = 256;      // 4 waves
static constexpr int W4 = W / 4;     // 128 float4 per row
static constexpr int ITER = ROWS * W4 / BLK;  // 16 float4 per thread

__global__ __launch_bounds__(BLK)
void bbox_partial(const float* __restrict__ mask, int* __restrict__ partials) {
    const int n = blockIdx.x;   // image
    const int g = blockIdx.y;   // row group
    const float4* base =
        (const float4*)(mask + (size_t)n * H * W + (size_t)g * ROWS * W);

    const int c  = threadIdx.x & (W4 - 1);   // fixed column group 0..127
    const int rb = threadIdx.x >> 7;         // row parity 0..1

    int ymin = INT_MAX, ymax = -1;
    float m0 = 0.f, m1 = 0.f, m2 = 0.f, m3 = 0.f;  // per-column max accumulators

    // i = tid + k*BLK  ->  row r = 2k + rb, col group = c (fixed).
    #pragma unroll
    for (int k = 0; k < ITER; k += 4) {
        // 4 independent loads issued before any consumption.
        float4 v0 = base[threadIdx.x + (k + 0) * BLK];
        float4 v1 = base[threadIdx.x + (k + 1) * BLK];
        float4 v2 = base[threadIdx.x + (k + 2) * BLK];
        float4 v3 = base[threadIdx.x + (k + 3) * BLK];

        float x0 = fmaxf(fmaxf(v0.x, v0.y), fmaxf(v0.z, v0.w));
        float x1 = fmaxf(fmaxf(v1.x, v1.y), fmaxf(v1.z, v1.w));
        float x2 = fmaxf(fmaxf(v2.x, v2.y), fmaxf(v2.z, v2.w));
        float x3 = fmaxf(fmaxf(v3.x, v3.y), fmaxf(v3.z, v3.w));

        int r = 2 * k + rb;  // row of v0 within this block's group
        if (x0 >= THRESH) { ymin = min(ymin, r + 0); ymax = max(ymax, r + 0); }
        if (x1 >= THRESH) { ymin = min(ymin, r + 2); ymax = max(ymax, r + 2); }
        if (x2 >= THRESH) { ymin = min(ymin, r + 4); ymax = max(ymax, r + 4); }
        if (x3 >= THRESH) { ymin = min(ymin, r + 6); ymax = max(ymax, r + 6); }

        m0 = fmaxf(fmaxf(m0, v0.x), fmaxf(v1.x, fmaxf(v2.x, v3.x)));
        m1 = fmaxf(fmaxf(m1, v0.y), fmaxf(v1.y, fmaxf(v2.y, v3.y)));
        m2 = fmaxf(fmaxf(m2, v0.z), fmaxf(v1.z, fmaxf(v2.z, v3.z)));
        m3 = fmaxf(fmaxf(m3, v0.w), fmaxf(v1.w, fmaxf(v2.w, v3.w)));
    }

    // Convert block-local row extent to global rows.
    if (ymax >= 0) { ymin += g * ROWS; ymax += g * ROWS; }

    // x extent from the accumulated column maxima (once, outside the loop).
    const int w = c << 2;
    int xmin = INT_MAX, xmax = -1;
    if (m0 >= THRESH) { xmin = w;                xmax = w;                }
    if (m1 >= THRESH) { xmin = min(xmin, w + 1); xmax = max(xmax, w + 1); }
    if (m2 >= THRESH) { xmin = min(xmin, w + 2); xmax = max(xmax, w + 2); }
    if (m3 >= THRESH) { xmin = min(xmin, w + 3); xmax = max(xmax, w + 3); }

    // Wave (64-lane) shuffle reduction.
    #pragma unroll
    for (int off = 32; off > 0; off >>= 1) {
        ymin = min(ymin, __shfl_down(ymin, off, 64));
        ymax = max(ymax, __shfl_down(ymax, off, 64));
        xmin = min(xmin, __shfl_down(xmin, off, 64));
        xmax = max(xmax, __shfl_down(xmax, off, 64));
    }

    __shared__ int s[BLK / 64][4];
    const int wave = threadIdx.x >> 6;
    const int lane = threadIdx.x & 63;
    if (lane == 0) {
        s[wave][0] = ymin; s[wave][1] = ymax; s[wave][2] = xmin; s[wave][3] = xmax;
    }
    __syncthreads();
    if (threadIdx.x == 0) {
        int a = s[0][0], b = s[0][1], cc = s[0][2], d = s[0][3];
        #pragma unroll
        for (int wv = 1; wv < BLK / 64; ++wv) {
            a  = min(a,  s[wv][0]); b = max(b, s[wv][1]);
            cc = min(cc, s[wv][2]); d = max(d, s[wv][3]);
        }
        ((int4*)partials)[n * G + g] = make_int4(a, b, cc, d);
    }
}

__global__ __launch_bounds__(128)
void bbox_final(const int* __restrict__ partials, int* __restrict__ out) {
    const int n = threadIdx.x;   // one block of 128 threads, one image each
    if (n >= N) return;
    int ymin = INT_MAX, ymax = -1, xmin = INT_MAX, xmax = -1;
    const int4* p = (const int4*)partials + n * G;
    #pragma unroll
    for (int g = 0; g < G; ++g) {
        int4 q = p[g];
        ymin = min(ymin, q.x); ymax = max(ymax, q.y);
        xmin = min(xmin, q.z); xmax = max(xmax, q.w);
    }
    int4 r;
    if (ymax < 0) r = make_int4(0, 0, H, W);                 // no hit anywhere
    else          r = make_int4(ymin, xmin, ymax + 1, xmax + 1);
    ((int4*)out)[n] = r;
}

extern "C" void kernel_launch(void* const* d_in, const int* in_sizes, int n_in,
                              void* d_out, int out_size, void* d_ws, size_t ws_size,
                              hipStream_t stream) {
    const float* mask = (const float*)d_in[0];
    int* partials = (int*)d_ws;              // N*G*4 ints = 32 KB, every slot written
    int* out = (int*)d_out;

    dim3 grid(N, G);
    bbox_partial<<<grid, BLK, 0, stream>>>(mask, partials);
    bbox_final<<<1, 128, 0, stream>>>(partials, out);
}

// Round 4
// 176.392 us; speedup vs baseline: 1.6099x; 1.0740x over previous
//
#include <hip/hip_runtime.h>
#include <climits>

// BoundingBox: mask [128,1,512,512] fp32 -> bbox [128,4] int32 (ymin,xmin,ymax+1,xmax+1)
// THRESH = 0.5; no hit anywhere -> (0,0,H,W).
//
// Two kernels, no atomics/fences (R1 showed fused atomic+fence tail costs ~100us).
// R3: maximal memory-level parallelism — all 8 float4 loads per thread issued
// before any use (single vmcnt wait point), non-temporal (streaming, no L2
// alloc), 4096 blocks for smooth ramp under harness writeback contention.

#define THRESH 0.5f

static constexpr int N = 128;
static constexpr int H = 512;
static constexpr int W = 512;
static constexpr int G = 32;         // row-groups per image -> 4096 blocks = 16/CU
static constexpr int ROWS = H / G;   // 16 rows per block
static constexpr int BLK = 256;      // 4 waves
static constexpr int W4 = W / 4;     // 128 float4 per row
static constexpr int ITER = ROWS * W4 / BLK;  // 8 float4 per thread

typedef float f32x4 __attribute__((ext_vector_type(4)));

__global__ __launch_bounds__(BLK)
void bbox_partial(const float* __restrict__ mask, int* __restrict__ partials) {
    const int n = blockIdx.x;   // image
    const int g = blockIdx.y;   // row group
    const f32x4* base =
        (const f32x4*)(mask + (size_t)n * H * W + (size_t)g * ROWS * W);

    const int c  = threadIdx.x & (W4 - 1);   // fixed column group 0..127
    const int rb = threadIdx.x >> 7;         // row parity 0..1

    // Issue ALL loads up front — 8 independent global_load_dwordx4 nt in flight.
    f32x4 v[ITER];
    #pragma unroll
    for (int k = 0; k < ITER; ++k)
        v[k] = __builtin_nontemporal_load(&base[threadIdx.x + k * BLK]);

    int ymin = INT_MAX, ymax = -1;
    float m0 = 0.f, m1 = 0.f, m2 = 0.f, m3 = 0.f;  // per-column max accumulators

    #pragma unroll
    for (int k = 0; k < ITER; ++k) {
        float mx = fmaxf(fmaxf(v[k].x, v[k].y), fmaxf(v[k].z, v[k].w));
        int r = 2 * k + rb;  // row of v[k] within this block's group
        if (mx >= THRESH) { ymin = min(ymin, r); ymax = max(ymax, r); }
        m0 = fmaxf(m0, v[k].x); m1 = fmaxf(m1, v[k].y);
        m2 = fmaxf(m2, v[k].z); m3 = fmaxf(m3, v[k].w);
    }

    // Block-local rows -> global rows.
    if (ymax >= 0) { ymin += g * ROWS; ymax += g * ROWS; }

    // x extent from accumulated column maxima (once, outside the loop).
    const int w = c << 2;
    int xmin = INT_MAX, xmax = -1;
    if (m0 >= THRESH) { xmin = w;                xmax = w;                }
    if (m1 >= THRESH) { xmin = min(xmin, w + 1); xmax = max(xmax, w + 1); }
    if (m2 >= THRESH) { xmin = min(xmin, w + 2); xmax = max(xmax, w + 2); }
    if (m3 >= THRESH) { xmin = min(xmin, w + 3); xmax = max(xmax, w + 3); }

    // Wave (64-lane) shuffle reduction.
    #pragma unroll
    for (int off = 32; off > 0; off >>= 1) {
        ymin = min(ymin, __shfl_down(ymin, off, 64));
        ymax = max(ymax, __shfl_down(ymax, off, 64));
        xmin = min(xmin, __shfl_down(xmin, off, 64));
        xmax = max(xmax, __shfl_down(xmax, off, 64));
    }

    __shared__ int s[BLK / 64][4];
    const int wave = threadIdx.x >> 6;
    const int lane = threadIdx.x & 63;
    if (lane == 0) {
        s[wave][0] = ymin; s[wave][1] = ymax; s[wave][2] = xmin; s[wave][3] = xmax;
    }
    __syncthreads();
    if (threadIdx.x == 0) {
        int a = s[0][0], b = s[0][1], cc = s[0][2], d = s[0][3];
        #pragma unroll
        for (int wv = 1; wv < BLK / 64; ++wv) {
            a  = min(a,  s[wv][0]); b = max(b, s[wv][1]);
            cc = min(cc, s[wv][2]); d = max(d, s[wv][3]);
        }
        ((int4*)partials)[n * G + g] = make_int4(a, b, cc, d);
    }
}

__global__ __launch_bounds__(128)
void bbox_final(const int* __restrict__ partials, int* __restrict__ out) {
    const int n = threadIdx.x;   // one block of 128 threads, one image each
    if (n >= N) return;
    int ymin = INT_MAX, ymax = -1, xmin = INT_MAX, xmax = -1;
    const int4* p = (const int4*)partials + n * G;
    #pragma unroll
    for (int g = 0; g < G; ++g) {
        int4 q = p[g];
        ymin = min(ymin, q.x); ymax = max(ymax, q.y);
        xmin = min(xmin, q.z); xmax = max(xmax, q.w);
    }
    int4 r;
    if (ymax < 0) r = make_int4(0, 0, H, W);                 // no hit anywhere
    else          r = make_int4(ymin, xmin, ymax + 1, xmax + 1);
    ((int4*)out)[n] = r;
}

extern "C" void kernel_launch(void* const* d_in, const int* in_sizes, int n_in,
                              void* d_out, int out_size, void* d_ws, size_t ws_size,
                              hipStream_t stream) {
    const float* mask = (const float*)d_in[0];
    int* partials = (int*)d_ws;              // N*G*4 ints = 64 KB, every slot written
    int* out = (int*)d_out;

    dim3 grid(N, G);
    bbox_partial<<<grid, BLK, 0, stream>>>(mask, partials);
    bbox_final<<<1, 128, 0, stream>>>(partials, out);
}